// Round 14
// baseline (76.132 us; speedup 1.0000x reference)
//
#include <hip/hip_runtime.h>
#include <hip/hip_bf16.h>
#include <cstdint>

#define IN_F 256
#define OUT_F 64
#define NB 4
#define NN 4096
#define ALPHA 0.2f
#define LOG2E 1.4426950408889634f

typedef __attribute__((ext_vector_type(4))) float f32x4;
typedef __attribute__((ext_vector_type(4))) int i32x4;
typedef __attribute__((ext_vector_type(8))) short bf16x8;

static __device__ __forceinline__ ushort f2bf(float x) {
  uint32_t u = __float_as_uint(x);
  uint32_t r = (u + 0x7fffu + ((u >> 16) & 1u)) >> 16;
  return (ushort)r;
}

// async global -> LDS, 16B per lane
static __device__ __forceinline__ void gl16(const void* g, void* l) {
  __builtin_amdgcn_global_load_lds(
      (const __attribute__((address_space(1))) void*)g,
      (__attribute__((address_space(3))) void*)l, 16, 0, 0);
}

// ---------------- Kernel 1: Wh = h@W + bias; Wh1/Wh2 = (Wh.a1/a2)*LOG2E; WhT bf16 [B][64][N]
__global__ __launch_bounds__(256) void k1_gemm(
    const float* __restrict__ h, const float* __restrict__ W,
    const float* __restrict__ a, const float* __restrict__ bias,
    ushort* __restrict__ WhT, float* __restrict__ Wh1, float* __restrict__ Wh2)
{
  __shared__ float hs[32][33];
  __shared__ float Ws[32][64];
  const int t  = threadIdx.x;
  const int tx = t & 15;
  const int ty = t >> 4;
  const int row0 = blockIdx.x * 32;

  float acc[2][4] = {};

  for (int k0 = 0; k0 < IN_F; k0 += 32) {
    {
      int r = t >> 3, c4 = t & 7;
      *(f32x4*)&hs[r][c4 * 4] =
          *(const f32x4*)(h + (size_t)(row0 + r) * IN_F + k0 + c4 * 4);
    }
    #pragma unroll
    for (int s = 0; s < 2; ++s) {
      int f4 = t + 256 * s;
      int kk = f4 >> 4, c4 = f4 & 15;
      *(f32x4*)&Ws[kk][c4 * 4] = *(const f32x4*)(W + (size_t)(k0 + kk) * OUT_F + c4 * 4);
    }
    __syncthreads();
    #pragma unroll 8
    for (int kk = 0; kk < 32; ++kk) {
      f32x4 bv = *(const f32x4*)&Ws[kk][tx * 4];
      float av0 = hs[ty * 2 + 0][kk];
      float av1 = hs[ty * 2 + 1][kk];
      #pragma unroll
      for (int j = 0; j < 4; ++j) {
        acc[0][j] += av0 * bv[j];
        acc[1][j] += av1 * bv[j];
      }
    }
    __syncthreads();
  }

  #pragma unroll
  for (int i = 0; i < 2; ++i) {
    int row = row0 + ty * 2 + i;
    float s1 = 0.f, s2 = 0.f;
    #pragma unroll
    for (int j = 0; j < 4; ++j) {
      float v = acc[i][j] + bias[tx * 4 + j];
      acc[i][j] = v;
      s1 += v * a[tx * 4 + j];
      s2 += v * a[64 + tx * 4 + j];
    }
    #pragma unroll
    for (int off = 1; off < 16; off <<= 1) {
      s1 += __shfl_xor(s1, off);
      s2 += __shfl_xor(s2, off);
    }
    if (tx == 0) { Wh1[row] = s1 * LOG2E; Wh2[row] = s2 * LOG2E; }
    int bb = row >> 12;
    int n  = row & 4095;
    #pragma unroll
    for (int j = 0; j < 4; ++j) {
      WhT[(((size_t)(bb * OUT_F + tx * 4 + j)) << 12) + n] = f2bf(acc[i][j]);
    }
  }
}

// ---------------- Kernel 2: fused masked softmax + PV, K-split x 2 blocks/CU
// grid (64, 4, 2): x = 64-row band, y = batch, z = K-half (2048 cols, 32 steps).
// 512 threads = 8 waves = (4 row-quarters) x (2 K-quarters of the 64-col step).
// Round-6 staging discipline, ring of 3 (24KB each) + 8KB wh2 = 81920 B LDS
// -> exactly 2 blocks/CU (163840 = full LDS). Counted vmcnt(3): 2 stages in
// flight during wait per block = 96 KB/CU across 2 blocks. Partial O/denom
// written to pacc/psum; k3 combines + ELU.
#define BUFSZ 24576
#define NDEPTH 3
#define WH2_OFF 73728    /* 3*24576 */
#define LDS_TOTAL 81920  /* + 8192 */
__global__ __launch_bounds__(512, 4) void k2_attn(
    const int* __restrict__ adj, const ushort* __restrict__ WhT,
    const float* __restrict__ Wh1, const float* __restrict__ Wh2,
    float* __restrict__ pacc, float* __restrict__ psum)
{
  extern __shared__ char smem[];
  const int t  = threadIdx.x;        // 0..511
  const int l  = t & 63;
  const int w  = t >> 6;             // 0..7
  const int rq = w >> 1;             // row quarter 0..3
  const int kq = w & 1;              // K half of the 64-col step
  const int g  = l >> 4;             // k-subgroup 0..3
  const int lr = l & 15;
  const int b  = blockIdx.y;
  const int r0 = blockIdx.x << 6;
  const int z  = blockIdx.z;         // K-half: cols z*2048 .. z*2048+2047

  const int   rowl = rq * 16 + lr;                   // block-local A row
  const float wh1  = Wh1[(b << 12) + r0 + rowl];     // already * LOG2E
  asm volatile("" :: "v"(wh1));

  // ---- staging source pointers (pre-inverse-swizzled, rule 21)
  const int*    adjb = adj + ((size_t)b << 24) + ((size_t)r0 << 12) + (z << 11);
  const ushort* whb  = WhT + ((size_t)(b * OUT_F) << 12) + (z << 11);
  const int rowA = t >> 4,           mlA = (t & 15) ^ (rowA & 7);
  const int rowB = (t + 512) >> 4,   mlB = (t & 15) ^ (rowB & 7);
  const int fW   = t >> 3,           mlW = (t & 7) ^ (fW & 7);
  const int*    srcA = adjb + (size_t)rowA * 4096 + mlA * 4;
  const int*    srcB = adjb + (size_t)rowB * 4096 + mlB * 4;
  const ushort* srcW = whb + ((size_t)fW << 12) + mlW * 8;
  const int ldsA = t << 4, ldsB = (t + 512) << 4, ldsW = 16384 + (t << 4);

  auto STAGE = [&](int s) {
    char* base = smem + (s % NDEPTH) * BUFSZ;
    gl16(srcA + s * 64, base + ldsA);
    gl16(srcB + s * 64, base + ldsB);
    gl16(srcW + s * 64, base + ldsW);
  };

  // ---- accumulators
  f32x4 a0 = {0.f,0.f,0.f,0.f}, a1 = {0.f,0.f,0.f,0.f};
  f32x4 a2 = {0.f,0.f,0.f,0.f}, a3 = {0.f,0.f,0.f,0.f};
  f32x4 as = {0.f,0.f,0.f,0.f};
  bf16x8 ones;
  #pragma unroll
  for (int i = 0; i < 8; ++i) ones[i] = (short)0x3F80;

  const int swzA = (rowl & 7) << 4;
  const int swzW = (lr & 7) << 4;
  const int offA0 = (kq * 128 + g * 32) ^ swzA;
  const int offA1 = (kq * 128 + g * 32 + 16) ^ swzA;
  const int offW  = (kq * 64 + g * 16) ^ swzW;

  auto COMPUTE = [&](int s) {
    const char* base = smem + (s % NDEPTH) * BUFSZ;
    i32x4 ad0 = *(const i32x4*)(base + rowl * 256 + offA0);
    i32x4 ad1 = *(const i32x4*)(base + rowl * 256 + offA1);
    const char* wb = base + 16384;
    bf16x8 b0 = *(const bf16x8*)(wb + (lr     ) * 128 + offW);
    bf16x8 b1 = *(const bf16x8*)(wb + (lr + 16) * 128 + offW);
    bf16x8 b2 = *(const bf16x8*)(wb + (lr + 32) * 128 + offW);
    bf16x8 b3 = *(const bf16x8*)(wb + (lr + 48) * 128 + offW);
    const char* w2b = smem + WH2_OFF + (s << 8) + kq * 128 + g * 32;
    f32x4 w20 = *(const f32x4*)(w2b);
    f32x4 w21 = *(const f32x4*)(w2b + 16);

    float p[8];
    #pragma unroll
    for (int i = 0; i < 8; ++i) {
      float w2 = (i < 4) ? w20[i] : w21[i - 4];
      int   am = (i < 4) ? ad0[i] : ad1[i - 4];
      float s_ = wh1 + w2;                                      // LOG2E-scaled
      float lk = fmaf(ALPHA, fminf(s_, 0.f), fmaxf(s_, 0.f));   // LeakyReLU
      float pe = exp2f(lk);                                     // unshifted, safe
      p[i] = (am > 0) ? pe : 0.0f;
    }
    union { bf16x8 v; uint32_t u[4]; } af;
    #pragma unroll
    for (int i = 0; i < 4; ++i)
      asm("v_cvt_pk_bf16_f32 %0, %1, %2" : "=v"(af.u[i]) : "v"(p[2*i]), "v"(p[2*i+1]));

    as = __builtin_amdgcn_mfma_f32_16x16x32_bf16(af.v, ones, as, 0, 0, 0);
    a0 = __builtin_amdgcn_mfma_f32_16x16x32_bf16(af.v, b0,   a0, 0, 0, 0);
    a1 = __builtin_amdgcn_mfma_f32_16x16x32_bf16(af.v, b1,   a1, 0, 0, 0);
    a2 = __builtin_amdgcn_mfma_f32_16x16x32_bf16(af.v, b2,   a2, 0, 0, 0);
    a3 = __builtin_amdgcn_mfma_f32_16x16x32_bf16(af.v, b3,   a3, 0, 0, 0);
  };

  // ---- prologue: wh2 K-half (1 gl16) + stages 0,1
  {
    const float* w2src = Wh2 + (b << 12) + (z << 11);
    gl16(w2src + (t << 2), smem + WH2_OFF + (t << 4));
  }
  STAGE(0);
  STAGE(1);

  // ---- main loop: 32 K-steps, ring of 3, 1 barrier/step, counted vmcnt.
  // wait at step s drains stage s (and wh2 at s=0), leaves s+1 in flight;
  // STAGE(s+2) issued post-compute -> 2 stages in flight during each wait.
  for (int s = 0; s < 32; ++s) {
    if (s < 31) asm volatile("s_waitcnt vmcnt(3)" ::: "memory");
    else        asm volatile("s_waitcnt vmcnt(0)" ::: "memory");
    __builtin_amdgcn_s_barrier();
    COMPUTE(s);
    if (s < 30) STAGE(s + 2);
  }

  // ---- epilogue: cross-kq combine, write PARTIAL O and denom
  __syncthreads();
  float* sacc = (float*)smem;                  // [2][64][68]
  float* ssum = (float*)(smem + 34816);        // [2][64]
  #pragma unroll
  for (int r = 0; r < 4; ++r) {
    int rr = rq * 16 + g * 4 + r;              // C/D: row = 4*(l>>4)+r, col = l&15
    float* dst = sacc + (kq * 64 + rr) * 68;
    dst[ 0 + lr] = a0[r];
    dst[16 + lr] = a1[r];
    dst[32 + lr] = a2[r];
    dst[48 + lr] = a3[r];
    if (lr == 0) ssum[kq * 64 + rr] = as[r];
  }
  __syncthreads();

  const int row = t >> 3;               // 0..63
  const int c0  = (t & 7) << 3;         // 0..56
  const float* p0 = sacc + row * 68;
  const float* p1 = sacc + (64 + row) * 68;
  float d = ssum[row] + ssum[64 + row];
  f32x4 o0, o1;
  #pragma unroll
  for (int j = 0; j < 4; ++j) {
    o0[j] = p0[c0 + j] + p1[c0 + j];
    o1[j] = p0[c0 + 4 + j] + p1[c0 + 4 + j];
  }
  size_t pb = ((size_t)z << 20) + (((size_t)(b << 12) + r0 + row) << 6) + c0;
  *(f32x4*)(pacc + pb)     = o0;
  *(f32x4*)(pacc + pb + 4) = o1;
  if ((t & 7) == 0) psum[(z << 14) + (b << 12) + r0 + row] = d;
}

// ---------------- Kernel 3: combine K-halves + softmax divide + ELU
__global__ __launch_bounds__(256) void k3_reduce(
    const float* __restrict__ pacc, const float* __restrict__ psum,
    float* __restrict__ out)
{
  const int e4  = (blockIdx.x * 256 + threadIdx.x) << 2;   // f32 index
  const int row = e4 >> 6;                                 // b*4096+n
  f32x4 v0 = *(const f32x4*)(pacc + e4);
  f32x4 v1 = *(const f32x4*)(pacc + (1 << 20) + e4);
  float inv = 1.0f / (psum[row] + psum[16384 + row]);
  f32x4 o;
  #pragma unroll
  for (int j = 0; j < 4; ++j) {
    float x = (v0[j] + v1[j]) * inv;
    o[j] = x > 0.f ? x : expm1f(x);
  }
  *(f32x4*)(out + e4) = o;
}

extern "C" void kernel_launch(void* const* d_in, const int* in_sizes, int n_in,
                              void* d_out, int out_size, void* d_ws, size_t ws_size,
                              hipStream_t stream) {
  const float* h    = (const float*)d_in[0];
  const int*   adj  = (const int*)d_in[1];
  const float* W    = (const float*)d_in[2];
  const float* a    = (const float*)d_in[3];
  const float* bias = (const float*)d_in[4];
  float* out = (float*)d_out;

  char* ws = (char*)d_ws;
  ushort* WhT = (ushort*)ws;                                   // 2 MB
  float*  Wh1 = (float*)(ws + (size_t)NB * OUT_F * NN * 2);    // 64 KB
  float*  Wh2 = Wh1 + NB * NN;                                 // 64 KB
  float*  pacc = Wh2 + NB * NN;                                // 8 MB (2 x 1M f32)
  float*  psum = pacc + (2 << 20);                             // 128 KB

  (void)hipFuncSetAttribute((const void*)k2_attn,
                            hipFuncAttributeMaxDynamicSharedMemorySize, LDS_TOTAL);

  k1_gemm<<<dim3(NB * NN / 32), 256, 0, stream>>>(h, W, a, bias, WhT, Wh1, Wh2);
  k2_attn<<<dim3(NN / 64, NB, 2), 512, LDS_TOTAL, stream>>>(adj, WhT, Wh1, Wh2, pacc, psum);
  k3_reduce<<<dim3(1024), 256, 0, stream>>>(pacc, psum, out);
}